// Round 3
// baseline (576.345 us; speedup 1.0000x reference)
//
#include <hip/hip_runtime.h>

// GHMC loss, round 8: keep r7's register select-chain core (no LDS RMW,
// no LDS atomics), fix the r7 regression: VGPR 96 -> <=64 via
// __launch_bounds__(256,8) and a 2-deep load batch instead of the 4-deep
// ping-pong (whose 64 live buffer regs halved occupancy). TLP (8 waves/SIMD)
// now hides HBM + trans latency instead of in-wave prefetch depth.
// Bit-identical accumulation order to r5/r7 (absmax 0).
//   loss = sum_b (S_b / C_b) / n_nonempty   (tot cancels algebraically)

#define THREADS 256
#define NB 10

__device__ __forceinline__ float bce(float x, float t) {
    // max(x,0) - x*t + log1p(exp(-|x|)); hw v_exp/v_log ~2ulp, negligible
    return fmaxf(x, 0.0f) - x * t + __logf(1.0f + __expf(-fabsf(x)));
}

__global__ __launch_bounds__(THREADS, 8) void ghmc_partial(
    const float4* __restrict__ p4, const float4* __restrict__ t4, int n4,
    const float* __restrict__ p1, const float* __restrict__ t1, long long ntot,
    double* __restrict__ g_sum, unsigned int* __restrict__ g_cnt) {

    const int tid = threadIdx.x;

    const float EDGE10 = 1.0f + 1e-6f;   // f32(edges[-1]) in the reference
    // 4 packed counters (one per float4 component): 10 six-bit fields each;
    // invalid elems go to bits 60..63 (never read). Flushed every 28 iters
    // (28*2 = 56 < 63 increments max per field between flushes).
    unsigned long long cc[4] = {0ull, 0ull, 0ull, 0ull};
    unsigned cnt[NB];
    float acc[NB];   // register bin sums
#pragma unroll
    for (int b = 0; b < NB; ++b) { cnt[b] = 0u; acc[b] = 0.0f; }

    // trunc(g*10) matches f32 searchsorted edges exactly (verified r3/r4,
    // absmax 0); g in [1.0,1+1e-6) -> idx 10 -> clamp 9 = reference bin 9.
    auto put = [&](float x, float t, unsigned long long& c) {
        const float g = fabsf(x - t);
        const float l = bce(x, t);
        int idx = (int)(g * 10.0f);
        idx = idx > 9 ? 9 : idx;
        idx = (g < EDGE10) ? idx : 10;   // 10 = discard (weight 0 in reference)
        c += 1ull << (6 * idx);
        // branchless register binning: 10 independent select+add chains,
        // compile-time indices (no scratch), no memory dependence
#pragma unroll
        for (int b = 0; b < NB; ++b)
            acc[b] += (idx == b) ? l : 0.0f;
    };
    auto flush_all = [&]() {
#pragma unroll
        for (int q = 0; q < 4; ++q) {
#pragma unroll
            for (int b = 0; b < NB; ++b)
                cnt[b] += (unsigned)((cc[q] >> (6 * b)) & 63ull);
            cc[q] = 0ull;
        }
    };

    // ---- block-contiguous partitioning (DRAM row locality) ----
    const int chunk = (n4 + (int)gridDim.x - 1) / (int)gridDim.x;
    const int start = blockIdx.x * chunk;
    const int end = min(start + chunk, n4);
    const int count = max(end - start, 0);
    const int full = count / THREADS;        // full block-strided iters (32)

    int k = 0;
    int since = 0;
    for (; k + 2 <= full; k += 2) {
        // batch both pairs' loads up front: 4 dwordx4 in flight, then compute
        const int id0 = start + k * THREADS + tid;
        const int id1 = id0 + THREADS;
        const float4 pa = p4[id0], ta = t4[id0];
        const float4 pb = p4[id1], tb = t4[id1];
        put(pa.x, ta.x, cc[0]); put(pa.y, ta.y, cc[1]);
        put(pa.z, ta.z, cc[2]); put(pa.w, ta.w, cc[3]);
        put(pb.x, tb.x, cc[0]); put(pb.y, tb.y, cc[1]);
        put(pb.z, tb.z, cc[2]); put(pb.w, tb.w, cc[3]);
        if (++since >= 28) { flush_all(); since = 0; }  // not taken at full=32
    }
    for (; k < full; ++k) {                  // odd leftover — not taken here
        const int id = start + k * THREADS + tid;
        const float4 pp = p4[id], tt = t4[id];
        put(pp.x, tt.x, cc[0]); put(pp.y, tt.y, cc[1]);
        put(pp.z, tt.z, cc[2]); put(pp.w, tt.w, cc[3]);
    }
    // tail float4s within the chunk — not taken for this shape
    {
        const int id = start + full * THREADS + tid;
        if (id < end) {
            const float4 pp = p4[id], tt = t4[id];
            put(pp.x, tt.x, cc[0]); put(pp.y, tt.y, cc[1]);
            put(pp.z, tt.z, cc[2]); put(pp.w, tt.w, cc[3]);
        }
    }
    flush_all();

    // scalar tail for ntot % 4 (not taken here): direct global atomics
    if (blockIdx.x == 0 && tid == 0) {
        for (long long j = (long long)n4 * 4; j < ntot; ++j) {
            const float x = p1[j], tt = t1[j];
            const float g = fabsf(x - tt);
            if (g < EDGE10) {
                int idx = (int)(g * 10.0f);
                idx = idx > 9 ? 9 : idx;
                atomicAdd(&g_sum[idx], (double)bce(x, tt));
                atomicAdd(&g_cnt[idx], 1u);
            }
        }
    }

    // 64-lane tree reduce from registers; block reduce; global atomics
#pragma unroll
    for (int off = 32; off > 0; off >>= 1) {
#pragma unroll
        for (int b = 0; b < NB; ++b) {
            acc[b] += __shfl_down(acc[b], off, 64);
            cnt[b] += __shfl_down(cnt[b], off, 64);
        }
    }

    __shared__ float w_sum[4][NB];
    __shared__ unsigned w_cnt[4][NB];
    const int wave = tid >> 6;
    const int lane = tid & 63;
    if (lane == 0) {
#pragma unroll
        for (int b = 0; b < NB; ++b) { w_sum[wave][b] = acc[b]; w_cnt[wave][b] = cnt[b]; }
    }
    __syncthreads();
    if (tid < NB) {
        const float fs = w_sum[0][tid] + w_sum[1][tid] + w_sum[2][tid] + w_sum[3][tid];
        const unsigned fc = w_cnt[0][tid] + w_cnt[1][tid] + w_cnt[2][tid] + w_cnt[3][tid];
        atomicAdd(&g_sum[tid], (double)fs);
        atomicAdd(&g_cnt[tid], fc);
    }
}

__global__ void ghmc_final(const double* __restrict__ g_sum,
                           const unsigned int* __restrict__ g_cnt,
                           float* __restrict__ out) {
    if (blockIdx.x == 0 && threadIdx.x == 0) {
        double loss = 0.0;
        int n = 0;
#pragma unroll
        for (int b = 0; b < NB; ++b) {
            const unsigned c = g_cnt[b];
            if (c > 0u) {
                n += 1;
                loss += g_sum[b] / (double)c;
            }
        }
        loss /= (n > 0) ? (double)n : 1.0;
        out[0] = (float)loss;
    }
}

extern "C" void kernel_launch(void* const* d_in, const int* in_sizes, int n_in,
                              void* d_out, int out_size, void* d_ws, size_t ws_size,
                              hipStream_t stream) {
    const float* pred = (const float*)d_in[0];
    const float* tgt  = (const float*)d_in[1];
    long long ntot = (long long)in_sizes[0];
    int n4 = (int)(ntot / 4);

    double* g_sum = (double*)d_ws;                                  // 10 doubles
    unsigned int* g_cnt = (unsigned int*)((char*)d_ws + NB * sizeof(double));

    hipMemsetAsync(d_ws, 0, NB * sizeof(double) + NB * sizeof(unsigned int),
                   stream);

    const int threads = THREADS;
    const int blocks = 2048;  // 8 blocks/CU, all resident; 128 KB chunk/block
    hipLaunchKernelGGL(ghmc_partial, dim3(blocks), dim3(threads), 0, stream,
                       (const float4*)pred, (const float4*)tgt, n4,
                       pred, tgt, ntot, g_sum, g_cnt);
    hipLaunchKernelGGL(ghmc_final, dim3(1), dim3(64), 0, stream,
                       g_sum, g_cnt, (float*)d_out);
}

// Round 4
// 535.699 us; speedup vs baseline: 1.0759x; 1.0759x over previous
//
#include <hip/hip_runtime.h>

// GHMC loss, round 9: register-pressure surgery. r7 (VGPR 96, occ 20%) and
// r8 (launch_bounds(256,8) -> VGPR 32 -> 438 MB scratch spill, 3x HBM
// traffic) bracket the optimum. Keep the register select-chain core
// bit-identical; relax the bound to (256,4) (spill-proof cap 128), pin
// the main loop with unroll 1 so live load-buffers stay at 16 VGPRs, and
// keep cnt[] dead during the loop (flush cadence 24 is provably safe:
// max 2 increments/field/iter -> 48 + leftovers < 63).
//   loss = sum_b (S_b / C_b) / n_nonempty   (tot cancels algebraically)

#define THREADS 256
#define NB 10

__device__ __forceinline__ float bce(float x, float t) {
    // max(x,0) - x*t + log1p(exp(-|x|)); hw v_exp/v_log ~2ulp, negligible
    return fmaxf(x, 0.0f) - x * t + __logf(1.0f + __expf(-fabsf(x)));
}

__global__ __launch_bounds__(THREADS, 4) void ghmc_partial(
    const float4* __restrict__ p4, const float4* __restrict__ t4, int n4,
    const float* __restrict__ p1, const float* __restrict__ t1, long long ntot,
    double* __restrict__ g_sum, unsigned int* __restrict__ g_cnt) {

    const int tid = threadIdx.x;

    const float EDGE10 = 1.0f + 1e-6f;   // f32(edges[-1]) in the reference
    // 4 packed counters (one per float4 component): 10 six-bit fields each;
    // invalid elems go to bits 60..63 (never read).
    unsigned long long cc[4] = {0ull, 0ull, 0ull, 0ull};
    unsigned cnt[NB];
    float acc[NB];   // register bin sums
#pragma unroll
    for (int b = 0; b < NB; ++b) { cnt[b] = 0u; acc[b] = 0.0f; }

    // trunc(g*10) matches f32 searchsorted edges exactly (verified r3/r4,
    // absmax 0); g in [1.0,1+1e-6) -> idx 10 -> clamp 9 = reference bin 9.
    auto put = [&](float x, float t, unsigned long long& c) {
        const float g = fabsf(x - t);
        const float l = bce(x, t);
        int idx = (int)(g * 10.0f);
        idx = idx > 9 ? 9 : idx;
        idx = (g < EDGE10) ? idx : 10;   // 10 = discard (weight 0 in reference)
        c += 1ull << (6 * idx);
        // branchless register binning: 10 independent select+add chains,
        // compile-time indices (no scratch), no memory dependence
#pragma unroll
        for (int b = 0; b < NB; ++b)
            acc[b] += (idx == b) ? l : 0.0f;
    };
    auto flush_all = [&]() {
#pragma unroll
        for (int q = 0; q < 4; ++q) {
#pragma unroll
            for (int b = 0; b < NB; ++b)
                cnt[b] += (unsigned)((cc[q] >> (6 * b)) & 63ull);
            cc[q] = 0ull;
        }
    };

    // ---- block-contiguous partitioning (DRAM row locality) ----
    const int chunk = (n4 + (int)gridDim.x - 1) / (int)gridDim.x;
    const int start = blockIdx.x * chunk;
    const int end = min(start + chunk, n4);
    const int count = max(end - start, 0);
    const int full = count / THREADS;        // full block-strided iters (32)

    int k = 0;
    int since = 0;
#pragma unroll 1   // pin: unrolling doubles live load-buffers -> VGPR blowup
    for (; k + 2 <= full; k += 2) {
        // batch both pairs' loads up front: 4 dwordx4 in flight, then compute
        const int id0 = start + k * THREADS + tid;
        const int id1 = id0 + THREADS;
        const float4 pa = p4[id0], ta = t4[id0];
        const float4 pb = p4[id1], tb = t4[id1];
        put(pa.x, ta.x, cc[0]); put(pa.y, ta.y, cc[1]);
        put(pa.z, ta.z, cc[2]); put(pa.w, ta.w, cc[3]);
        put(pb.x, tb.x, cc[0]); put(pb.y, tb.y, cc[1]);
        put(pb.z, tb.z, cc[2]); put(pb.w, tb.w, cc[3]);
        if (++since >= 24) { flush_all(); since = 0; }  // not taken at full=32
    }
#pragma unroll 1
    for (; k < full; ++k) {                  // odd leftover — not taken here
        const int id = start + k * THREADS + tid;
        const float4 pp = p4[id], tt = t4[id];
        put(pp.x, tt.x, cc[0]); put(pp.y, tt.y, cc[1]);
        put(pp.z, tt.z, cc[2]); put(pp.w, tt.w, cc[3]);
    }
    // tail float4s within the chunk — not taken for this shape
    {
        const int id = start + full * THREADS + tid;
        if (id < end) {
            const float4 pp = p4[id], tt = t4[id];
            put(pp.x, tt.x, cc[0]); put(pp.y, tt.y, cc[1]);
            put(pp.z, tt.z, cc[2]); put(pp.w, tt.w, cc[3]);
        }
    }
    flush_all();

    // scalar tail for ntot % 4 (not taken here): direct global atomics
    if (blockIdx.x == 0 && tid == 0) {
        for (long long j = (long long)n4 * 4; j < ntot; ++j) {
            const float x = p1[j], tt = t1[j];
            const float g = fabsf(x - tt);
            if (g < EDGE10) {
                int idx = (int)(g * 10.0f);
                idx = idx > 9 ? 9 : idx;
                atomicAdd(&g_sum[idx], (double)bce(x, tt));
                atomicAdd(&g_cnt[idx], 1u);
            }
        }
    }

    // 64-lane tree reduce from registers; block reduce; global atomics
#pragma unroll
    for (int off = 32; off > 0; off >>= 1) {
#pragma unroll
        for (int b = 0; b < NB; ++b) {
            acc[b] += __shfl_down(acc[b], off, 64);
            cnt[b] += __shfl_down(cnt[b], off, 64);
        }
    }

    __shared__ float w_sum[4][NB];
    __shared__ unsigned w_cnt[4][NB];
    const int wave = tid >> 6;
    const int lane = tid & 63;
    if (lane == 0) {
#pragma unroll
        for (int b = 0; b < NB; ++b) { w_sum[wave][b] = acc[b]; w_cnt[wave][b] = cnt[b]; }
    }
    __syncthreads();
    if (tid < NB) {
        const float fs = w_sum[0][tid] + w_sum[1][tid] + w_sum[2][tid] + w_sum[3][tid];
        const unsigned fc = w_cnt[0][tid] + w_cnt[1][tid] + w_cnt[2][tid] + w_cnt[3][tid];
        atomicAdd(&g_sum[tid], (double)fs);
        atomicAdd(&g_cnt[tid], fc);
    }
}

__global__ void ghmc_final(const double* __restrict__ g_sum,
                           const unsigned int* __restrict__ g_cnt,
                           float* __restrict__ out) {
    if (blockIdx.x == 0 && threadIdx.x == 0) {
        double loss = 0.0;
        int n = 0;
#pragma unroll
        for (int b = 0; b < NB; ++b) {
            const unsigned c = g_cnt[b];
            if (c > 0u) {
                n += 1;
                loss += g_sum[b] / (double)c;
            }
        }
        loss /= (n > 0) ? (double)n : 1.0;
        out[0] = (float)loss;
    }
}

extern "C" void kernel_launch(void* const* d_in, const int* in_sizes, int n_in,
                              void* d_out, int out_size, void* d_ws, size_t ws_size,
                              hipStream_t stream) {
    const float* pred = (const float*)d_in[0];
    const float* tgt  = (const float*)d_in[1];
    long long ntot = (long long)in_sizes[0];
    int n4 = (int)(ntot / 4);

    double* g_sum = (double*)d_ws;                                  // 10 doubles
    unsigned int* g_cnt = (unsigned int*)((char*)d_ws + NB * sizeof(double));

    hipMemsetAsync(d_ws, 0, NB * sizeof(double) + NB * sizeof(unsigned int),
                   stream);

    const int threads = THREADS;
    const int blocks = 2048;  // 128 KB chunk/block, DRAM-row-contiguous
    hipLaunchKernelGGL(ghmc_partial, dim3(blocks), dim3(threads), 0, stream,
                       (const float4*)pred, (const float4*)tgt, n4,
                       pred, tgt, ntot, g_sum, g_cnt);
    hipLaunchKernelGGL(ghmc_final, dim3(1), dim3(64), 0, stream,
                       g_sum, g_cnt, (float*)d_out);
}

// Round 5
// 526.882 us; speedup vs baseline: 1.0939x; 1.0167x over previous
//
#include <hip/hip_runtime.h>

// GHMC loss, round 10: the ledger across r5/r7/r9 shows ~90-105us of
// invariant stall time regardless of accumulation structure -> unhidden
// HBM load latency (loads issued at top of iter k, consumed immediately;
// wave duty ~38%). Fix: 1-deep software pipeline -- issue next pair's 4
// dwordx4 loads BEFORE computing the current pair. Static A/B buffer
// names, unroll-1 pinned (r7's VGPR blowup was the unroller tripling
// buffer liveness). Compute core bit-identical to r5/r7/r9 (absmax 0).
//   loss = sum_b (S_b / C_b) / n_nonempty   (tot cancels algebraically)

#define THREADS 256
#define NB 10

__device__ __forceinline__ float bce(float x, float t) {
    // max(x,0) - x*t + log1p(exp(-|x|)); hw v_exp/v_log ~2ulp, negligible
    return fmaxf(x, 0.0f) - x * t + __logf(1.0f + __expf(-fabsf(x)));
}

__global__ __launch_bounds__(THREADS, 4) void ghmc_partial(
    const float4* __restrict__ p4, const float4* __restrict__ t4, int n4,
    const float* __restrict__ p1, const float* __restrict__ t1, long long ntot,
    double* __restrict__ g_sum, unsigned int* __restrict__ g_cnt) {

    const int tid = threadIdx.x;

    const float EDGE10 = 1.0f + 1e-6f;   // f32(edges[-1]) in the reference
    // 4 packed counters (one per float4 component): 10 six-bit fields each;
    // invalid elems go to bits 60..63 (never read).
    unsigned long long cc[4] = {0ull, 0ull, 0ull, 0ull};
    unsigned cnt[NB];
    float acc[NB];   // register bin sums
#pragma unroll
    for (int b = 0; b < NB; ++b) { cnt[b] = 0u; acc[b] = 0.0f; }

    // trunc(g*10) matches f32 searchsorted edges exactly (verified r3/r4,
    // absmax 0); g in [1.0,1+1e-6) -> idx 10 -> clamp 9 = reference bin 9.
    auto put = [&](float x, float t, unsigned long long& c) {
        const float g = fabsf(x - t);
        const float l = bce(x, t);
        int idx = (int)(g * 10.0f);
        idx = idx > 9 ? 9 : idx;
        idx = (g < EDGE10) ? idx : 10;   // 10 = discard (weight 0 in reference)
        c += 1ull << (6 * idx);
        // branchless register binning: 10 independent select+add chains,
        // compile-time indices (no scratch), no memory dependence
#pragma unroll
        for (int b = 0; b < NB; ++b)
            acc[b] += (idx == b) ? l : 0.0f;
    };
    auto flush_all = [&]() {
#pragma unroll
        for (int q = 0; q < 4; ++q) {
#pragma unroll
            for (int b = 0; b < NB; ++b)
                cnt[b] += (unsigned)((cc[q] >> (6 * b)) & 63ull);
            cc[q] = 0ull;
        }
    };

    // ---- block-contiguous partitioning (DRAM row locality) ----
    const int chunk = (n4 + (int)gridDim.x - 1) / (int)gridDim.x;
    const int start = blockIdx.x * chunk;
    const int end = min(start + chunk, n4);
    const int count = max(end - start, 0);
    const int full = count / THREADS;        // full block-strided iters (32)
    const int npairs = full / 2;             // paired iters (16)

    // two static buffer sets: a "pair" = float4s at k=2p and k=2p+1
    float4 PA0, TA0, PA1, TA1, PB0, TB0, PB1, TB1;
    auto loadA = [&](int p) {
        const int id = start + (2 * p) * THREADS + tid;
        PA0 = p4[id]; TA0 = t4[id];
        PA1 = p4[id + THREADS]; TA1 = t4[id + THREADS];
    };
    auto loadB = [&](int p) {
        const int id = start + (2 * p) * THREADS + tid;
        PB0 = p4[id]; TB0 = t4[id];
        PB1 = p4[id + THREADS]; TB1 = t4[id + THREADS];
    };
    auto procA = [&]() {
        put(PA0.x, TA0.x, cc[0]); put(PA0.y, TA0.y, cc[1]);
        put(PA0.z, TA0.z, cc[2]); put(PA0.w, TA0.w, cc[3]);
        put(PA1.x, TA1.x, cc[0]); put(PA1.y, TA1.y, cc[1]);
        put(PA1.z, TA1.z, cc[2]); put(PA1.w, TA1.w, cc[3]);
    };
    auto procB = [&]() {
        put(PB0.x, TB0.x, cc[0]); put(PB0.y, TB0.y, cc[1]);
        put(PB0.z, TB0.z, cc[2]); put(PB0.w, TB0.w, cc[3]);
        put(PB1.x, TB1.x, cc[0]); put(PB1.y, TB1.y, cc[1]);
        put(PB1.z, TB1.z, cc[2]); put(PB1.w, TB1.w, cc[3]);
    };

    int since = 0;
    int p = 0;
    if (npairs > 0) loadA(0);
#pragma unroll 1   // pin: unrolling multiplies live load-buffers -> VGPR blowup
    for (; p + 2 <= npairs; p += 2) {
        loadB(p + 1);                 // prefetch: in flight during procA
        procA();                      // pair p
        if (p + 2 < npairs) loadA(p + 2);  // prefetch: in flight during procB
        procB();                      // pair p+1
        // flush cadence: 4 increments/field per loop iter; 12*4=48, plus
        // post-loop worst case (odd pair 2 + leftover 1 + tail 1) < 63.
        if (++since >= 12) { flush_all(); since = 0; }  // not taken at npairs=16
    }
    if (p < npairs) procA();          // odd npairs: final pair already in A

#pragma unroll 1
    for (int k = npairs * 2; k < full; ++k) {   // odd leftover — not taken here
        const int id = start + k * THREADS + tid;
        const float4 pp = p4[id], tt = t4[id];
        put(pp.x, tt.x, cc[0]); put(pp.y, tt.y, cc[1]);
        put(pp.z, tt.z, cc[2]); put(pp.w, tt.w, cc[3]);
    }
    // tail float4s within the chunk — not taken for this shape
    {
        const int id = start + full * THREADS + tid;
        if (id < end) {
            const float4 pp = p4[id], tt = t4[id];
            put(pp.x, tt.x, cc[0]); put(pp.y, tt.y, cc[1]);
            put(pp.z, tt.z, cc[2]); put(pp.w, tt.w, cc[3]);
        }
    }
    flush_all();

    // scalar tail for ntot % 4 (not taken here): direct global atomics
    if (blockIdx.x == 0 && tid == 0) {
        for (long long j = (long long)n4 * 4; j < ntot; ++j) {
            const float x = p1[j], tt = t1[j];
            const float g = fabsf(x - tt);
            if (g < EDGE10) {
                int idx = (int)(g * 10.0f);
                idx = idx > 9 ? 9 : idx;
                atomicAdd(&g_sum[idx], (double)bce(x, tt));
                atomicAdd(&g_cnt[idx], 1u);
            }
        }
    }

    // 64-lane tree reduce from registers; block reduce; global atomics
#pragma unroll
    for (int off = 32; off > 0; off >>= 1) {
#pragma unroll
        for (int b = 0; b < NB; ++b) {
            acc[b] += __shfl_down(acc[b], off, 64);
            cnt[b] += __shfl_down(cnt[b], off, 64);
        }
    }

    __shared__ float w_sum[4][NB];
    __shared__ unsigned w_cnt[4][NB];
    const int wave = tid >> 6;
    const int lane = tid & 63;
    if (lane == 0) {
#pragma unroll
        for (int b = 0; b < NB; ++b) { w_sum[wave][b] = acc[b]; w_cnt[wave][b] = cnt[b]; }
    }
    __syncthreads();
    if (tid < NB) {
        const float fs = w_sum[0][tid] + w_sum[1][tid] + w_sum[2][tid] + w_sum[3][tid];
        const unsigned fc = w_cnt[0][tid] + w_cnt[1][tid] + w_cnt[2][tid] + w_cnt[3][tid];
        atomicAdd(&g_sum[tid], (double)fs);
        atomicAdd(&g_cnt[tid], fc);
    }
}

__global__ void ghmc_final(const double* __restrict__ g_sum,
                           const unsigned int* __restrict__ g_cnt,
                           float* __restrict__ out) {
    if (blockIdx.x == 0 && threadIdx.x == 0) {
        double loss = 0.0;
        int n = 0;
#pragma unroll
        for (int b = 0; b < NB; ++b) {
            const unsigned c = g_cnt[b];
            if (c > 0u) {
                n += 1;
                loss += g_sum[b] / (double)c;
            }
        }
        loss /= (n > 0) ? (double)n : 1.0;
        out[0] = (float)loss;
    }
}

extern "C" void kernel_launch(void* const* d_in, const int* in_sizes, int n_in,
                              void* d_out, int out_size, void* d_ws, size_t ws_size,
                              hipStream_t stream) {
    const float* pred = (const float*)d_in[0];
    const float* tgt  = (const float*)d_in[1];
    long long ntot = (long long)in_sizes[0];
    int n4 = (int)(ntot / 4);

    double* g_sum = (double*)d_ws;                                  // 10 doubles
    unsigned int* g_cnt = (unsigned int*)((char*)d_ws + NB * sizeof(double));

    hipMemsetAsync(d_ws, 0, NB * sizeof(double) + NB * sizeof(unsigned int),
                   stream);

    const int threads = THREADS;
    const int blocks = 2048;  // 128 KB chunk/block, DRAM-row-contiguous
    hipLaunchKernelGGL(ghmc_partial, dim3(blocks), dim3(threads), 0, stream,
                       (const float4*)pred, (const float4*)tgt, n4,
                       pred, tgt, ntot, g_sum, g_cnt);
    hipLaunchKernelGGL(ghmc_final, dim3(1), dim3(64), 0, stream,
                       g_sum, g_cnt, (float*)d_out);
}

// Round 6
// 520.518 us; speedup vs baseline: 1.1073x; 1.0122x over previous
//
#include <hip/hip_runtime.h>

// GHMC loss, round 11: ledger (r5/r7/r9/r10) shows prefetch depth and VGPR
// move nothing; wall = VALU-busy + structure-dependent stall. r5's LDS core
// has the least VALU (no 30-inst select chain) but serialized per-element
// LDS RMW (read -> ~64cy wait -> add -> write, next read can't hoist past
// prev write: runtime idx aliasing). Fix: batch 4 reads up front (one
// latency for 4 elems), repair same-address collisions in registers with a
// cndmask chain (exact sequential semantics), then 4 in-order writes.
// Bit-identical to r5's per-(thread,bin) sums -> absmax 0.
//   loss = sum_b (S_b / C_b) / n_nonempty   (tot cancels algebraically)

#define THREADS 256
#define LSTRIDE 11   // 10 bins + discard slot; odd stride -> <=2-way bank alias
#define NB 10

__device__ __forceinline__ float bce(float x, float t) {
    // max(x,0) - x*t + log1p(exp(-|x|)); hw v_exp/v_log ~2ulp, negligible
    return fmaxf(x, 0.0f) - x * t + __logf(1.0f + __expf(-fabsf(x)));
}

__global__ __launch_bounds__(THREADS, 4) void ghmc_partial(
    const float4* __restrict__ p4, const float4* __restrict__ t4, int n4,
    const float* __restrict__ p1, const float* __restrict__ t1, long long ntot,
    double* __restrict__ g_sum, unsigned int* __restrict__ g_cnt) {

    __shared__ float lds[THREADS * LSTRIDE];
    const int tid = threadIdx.x;
    float* slots = &lds[tid * LSTRIDE];
#pragma unroll
    for (int b = 0; b < LSTRIDE; ++b) slots[b] = 0.0f;
    // no barrier: regions thread-private; LDS pipe in-order per wave

    const float EDGE10 = 1.0f + 1e-6f;   // f32(edges[-1]) in the reference
    // 4 packed counters (one per float4 component): 10 six-bit fields each;
    // invalid elems go to bits 60..63 (never read).
    unsigned long long cc[4] = {0ull, 0ull, 0ull, 0ull};
    unsigned cnt[NB];
#pragma unroll
    for (int b = 0; b < NB; ++b) cnt[b] = 0u;

    // trunc(g*10) matches f32 searchsorted edges exactly (verified r3/r4,
    // absmax 0); g in [1.0,1+1e-6) -> idx 10 -> clamp 9 = reference bin 9.
    auto classify = [&](float x, float t, float& l, int& idx) {
        const float g = fabsf(x - t);
        l = bce(x, t);
        int i = (int)(g * 10.0f);
        i = i > 9 ? 9 : i;
        idx = (g < EDGE10) ? i : 10;     // 10 = discard (weight 0 in reference)
    };

    // 4-wide exact LDS RMW: one read-latency for 4 elements; register
    // cndmask chain replays sequential same-address semantics exactly.
    auto put4 = [&](float x0, float t0, float x1, float t1,
                    float x2, float t2, float x3, float t3) {
        float l0, l1, l2, l3;
        int i0, i1, i2, i3;
        classify(x0, t0, l0, i0);
        classify(x1, t1, l1, i1);
        classify(x2, t2, l2, i2);
        classify(x3, t3, l3, i3);
        cc[0] += 1ull << (6 * i0);
        cc[1] += 1ull << (6 * i1);
        cc[2] += 1ull << (6 * i2);
        cc[3] += 1ull << (6 * i3);
        // batched reads: issued back-to-back, one ~64cy wait covers all 4
        const float r0 = slots[i0];
        const float r1 = slots[i1];
        const float r2 = slots[i2];
        const float r3 = slots[i3];
        // exact sequential fixup: pick the latest prior value for same addr
        const float v0 = r0 + l0;
        const float s1 = (i1 == i0) ? v0 : r1;
        const float v1 = s1 + l1;
        const float s2 = (i2 == i1) ? v1 : ((i2 == i0) ? v0 : r2);
        const float v2 = s2 + l2;
        const float s3 = (i3 == i2) ? v2
                        : ((i3 == i1) ? v1 : ((i3 == i0) ? v0 : r3));
        const float v3 = s3 + l3;
        // in-order writes: LDS pipe in-order per wave -> last write wins
        slots[i0] = v0;
        slots[i1] = v1;
        slots[i2] = v2;
        slots[i3] = v3;
    };
    // sequential single-element put for tails (trivially exact)
    auto put1 = [&](float x, float t, unsigned long long& c) {
        float l; int idx;
        classify(x, t, l, idx);
        c += 1ull << (6 * idx);
        slots[idx] += l;
    };
    auto flush_all = [&]() {
#pragma unroll
        for (int q = 0; q < 4; ++q) {
#pragma unroll
            for (int b = 0; b < NB; ++b)
                cnt[b] += (unsigned)((cc[q] >> (6 * b)) & 63ull);
            cc[q] = 0ull;
        }
    };

    // ---- block-contiguous partitioning (DRAM row locality) ----
    const int chunk = (n4 + (int)gridDim.x - 1) / (int)gridDim.x;
    const int start = blockIdx.x * chunk;
    const int end = min(start + chunk, n4);
    const int count = max(end - start, 0);
    const int full = count / THREADS;        // full block-strided iters (32)
    const int npairs = full / 2;             // paired iters (16)

    // 1-deep prefetch with static A/B buffers (cheap; keep loads early)
    float4 PA0, TA0, PA1, TA1, PB0, TB0, PB1, TB1;
    auto loadA = [&](int p) {
        const int id = start + (2 * p) * THREADS + tid;
        PA0 = p4[id]; TA0 = t4[id];
        PA1 = p4[id + THREADS]; TA1 = t4[id + THREADS];
    };
    auto loadB = [&](int p) {
        const int id = start + (2 * p) * THREADS + tid;
        PB0 = p4[id]; TB0 = t4[id];
        PB1 = p4[id + THREADS]; TB1 = t4[id + THREADS];
    };
    auto procA = [&]() {
        put4(PA0.x, TA0.x, PA0.y, TA0.y, PA0.z, TA0.z, PA0.w, TA0.w);
        put4(PA1.x, TA1.x, PA1.y, TA1.y, PA1.z, TA1.z, PA1.w, TA1.w);
    };
    auto procB = [&]() {
        put4(PB0.x, TB0.x, PB0.y, TB0.y, PB0.z, TB0.z, PB0.w, TB0.w);
        put4(PB1.x, TB1.x, PB1.y, TB1.y, PB1.z, TB1.z, PB1.w, TB1.w);
    };

    int since = 0;
    int p = 0;
    if (npairs > 0) loadA(0);
#pragma unroll 1   // pin: unrolling multiplies live load-buffers -> VGPR blowup
    for (; p + 2 <= npairs; p += 2) {
        loadB(p + 1);
        procA();
        if (p + 2 < npairs) loadA(p + 2);
        procB();
        // cadence: 4 increments/field/iter max; 12*4=48 + post-loop
        // (odd pair 2 + leftover 1 + tail 1) < 63
        if (++since >= 12) { flush_all(); since = 0; }  // not taken at npairs=16
    }
    if (p < npairs) procA();          // odd npairs: final pair already in A

#pragma unroll 1
    for (int k = npairs * 2; k < full; ++k) {   // odd leftover — not taken here
        const int id = start + k * THREADS + tid;
        const float4 pp = p4[id], tt = t4[id];
        put1(pp.x, tt.x, cc[0]); put1(pp.y, tt.y, cc[1]);
        put1(pp.z, tt.z, cc[2]); put1(pp.w, tt.w, cc[3]);
    }
    // tail float4s within the chunk — not taken for this shape
    {
        const int id = start + full * THREADS + tid;
        if (id < end) {
            const float4 pp = p4[id], tt = t4[id];
            put1(pp.x, tt.x, cc[0]); put1(pp.y, tt.y, cc[1]);
            put1(pp.z, tt.z, cc[2]); put1(pp.w, tt.w, cc[3]);
        }
    }
    flush_all();

    // scalar tail for ntot % 4 (not taken here): direct global atomics
    if (blockIdx.x == 0 && tid == 0) {
        for (long long j = (long long)n4 * 4; j < ntot; ++j) {
            const float x = p1[j], tt = t1[j];
            const float g = fabsf(x - tt);
            if (g < EDGE10) {
                int idx = (int)(g * 10.0f);
                idx = idx > 9 ? 9 : idx;
                atomicAdd(&g_sum[idx], (double)bce(x, tt));
                atomicAdd(&g_cnt[idx], 1u);
            }
        }
    }

    // read back own bins; 64-lane tree reduce; block reduce; global atomics
    float s[NB];
#pragma unroll
    for (int b = 0; b < NB; ++b) s[b] = slots[b];
#pragma unroll
    for (int off = 32; off > 0; off >>= 1) {
#pragma unroll
        for (int b = 0; b < NB; ++b) {
            s[b] += __shfl_down(s[b], off, 64);
            cnt[b] += __shfl_down(cnt[b], off, 64);
        }
    }

    __shared__ float w_sum[4][NB];
    __shared__ unsigned w_cnt[4][NB];
    const int wave = tid >> 6;
    const int lane = tid & 63;
    if (lane == 0) {
#pragma unroll
        for (int b = 0; b < NB; ++b) { w_sum[wave][b] = s[b]; w_cnt[wave][b] = cnt[b]; }
    }
    __syncthreads();
    if (tid < NB) {
        const float fs = w_sum[0][tid] + w_sum[1][tid] + w_sum[2][tid] + w_sum[3][tid];
        const unsigned fc = w_cnt[0][tid] + w_cnt[1][tid] + w_cnt[2][tid] + w_cnt[3][tid];
        atomicAdd(&g_sum[tid], (double)fs);
        atomicAdd(&g_cnt[tid], fc);
    }
}

__global__ void ghmc_final(const double* __restrict__ g_sum,
                           const unsigned int* __restrict__ g_cnt,
                           float* __restrict__ out) {
    if (blockIdx.x == 0 && threadIdx.x == 0) {
        double loss = 0.0;
        int n = 0;
#pragma unroll
        for (int b = 0; b < NB; ++b) {
            const unsigned c = g_cnt[b];
            if (c > 0u) {
                n += 1;
                loss += g_sum[b] / (double)c;
            }
        }
        loss /= (n > 0) ? (double)n : 1.0;
        out[0] = (float)loss;
    }
}

extern "C" void kernel_launch(void* const* d_in, const int* in_sizes, int n_in,
                              void* d_out, int out_size, void* d_ws, size_t ws_size,
                              hipStream_t stream) {
    const float* pred = (const float*)d_in[0];
    const float* tgt  = (const float*)d_in[1];
    long long ntot = (long long)in_sizes[0];
    int n4 = (int)(ntot / 4);

    double* g_sum = (double*)d_ws;                                  // 10 doubles
    unsigned int* g_cnt = (unsigned int*)((char*)d_ws + NB * sizeof(double));

    hipMemsetAsync(d_ws, 0, NB * sizeof(double) + NB * sizeof(unsigned int),
                   stream);

    const int threads = THREADS;
    const int blocks = 2048;  // keep grid fixed: element->thread mapping
                              // unchanged from r5 (bit-exact partials)
    hipLaunchKernelGGL(ghmc_partial, dim3(blocks), dim3(threads), 0, stream,
                       (const float4*)pred, (const float4*)tgt, n4,
                       pred, tgt, ntot, g_sum, g_cnt);
    hipLaunchKernelGGL(ghmc_final, dim3(1), dim3(64), 0, stream,
                       g_sum, g_cnt, (float*)d_out);
}